// Round 3
// baseline (383.544 us; speedup 1.0000x reference)
//
#include <hip/hip_runtime.h>
#include <cstdint>
#include <cstddef>

#define BN_EPS 1e-5f
#define BATCH 8192

typedef unsigned long long u64;
typedef uint32_t u32;

// ---------------- prep kernels ----------------

// Fold BN into per-channel (inv, shift): y = x*inv + shift; sign(y) is all
// downstream layers need (Hardtanh clip preserves sign).
__global__ void prep_bn_all(const float* g1, const float* be1, const float* m1, const float* v1,
                            const float* g2, const float* be2, const float* m2, const float* v2,
                            const float* g3, const float* be3, const float* m3, const float* v3,
                            const float* g4, const float* be4, const float* m4, const float* v4,
                            float* inv1, float* sh1, float* inv2, float* sh2,
                            float* inv3, float* sh3, float* inv4, float* sh4) {
    int t = threadIdx.x;  // 128 threads
    if (t < 32) { float iv = g1[t] * rsqrtf(v1[t] + BN_EPS); inv1[t] = iv; sh1[t] = be1[t] - m1[t] * iv; }
    if (t < 64) { float iv = g2[t] * rsqrtf(v2[t] + BN_EPS); inv2[t] = iv; sh2[t] = be2[t] - m2[t] * iv; }
    if (t < 128) { float iv = g3[t] * rsqrtf(v3[t] + BN_EPS); inv3[t] = iv; sh3[t] = be3[t] - m3[t] * iv; }
    if (t < 128) { float iv = g4[t] * rsqrtf(v4[t] + BN_EPS); inv4[t] = iv; sh4[t] = be4[t] - m4[t] * iv; }
}

// Pack binarized weights into bit words (bit = 1 means weight >= 0 i.e. +1).
__global__ void prep_pack(const float* w1, const float* w2, const float* w3, const float* w4,
                          const float* wf,
                          float* s1, u32* wt2, u64* wt3, u64* wt4, u64* wtf) {
    int t = blockIdx.x * blockDim.x + threadIdx.x;   // up to 1536 (6 blocks x 256)
    // layer1 signs as +-1.0f floats: [32 co][9 k]
    if (t < 288) s1[t] = (w1[t] >= 0.f) ? 1.f : -1.f;
    // layer2: [64 co][3 kw] words over 32 ci; w2 OIHW (64,32,1,3)
    if (t < 192) {
        int co = t / 3, kw = t % 3;
        u32 wb = 0;
        for (int ci = 0; ci < 32; ++ci)
            wb |= (u32)(w2[(co * 32 + ci) * 3 + kw] >= 0.f) << ci;
        wt2[t] = wb;
    }
    // layer3: [128 co][3 kw] words over 64 ci; w3 (128,64,1,3)
    if (t < 384) {
        int co = t / 3, kw = t % 3;
        u64 wb = 0;
        for (int ci = 0; ci < 64; ++ci)
            wb |= (u64)(w3[(co * 64 + ci) * 3 + kw] >= 0.f) << ci;
        wt3[t] = wb;
    }
    // layer4: [(co*6+h)*2+j] words, bit cb = ci - j*64; w4 (128,128,6,1)
    if (t < 1536) {
        int j = t & 1, ch = t >> 1;
        int co = ch / 6, h = ch % 6;
        u64 wb = 0;
        for (int cb = 0; cb < 64; ++cb) {
            int ci = j * 64 + cb;
            wb |= (u64)(w4[(co * 128 + ci) * 6 + h] >= 0.f) << cb;
        }
        wt4[t] = wb;
    }
    // fc: [10 o][32 wi] words; wf (10,2048), feature f = co*16+w
    if (t < 320) {
        int o = t / 32, wi = t % 32;
        u64 wb = 0;
        for (int fb = 0; fb < 64; ++fb)
            wb |= (u64)(wf[o * 2048 + wi * 64 + fb] >= 0.f) << fb;
        wtf[t] = wb;
    }
}

// ---------------- layer 1: fp32 conv (1x9, stride 2, pad 4) + BN sign + pool-OR ----------------
// One thread per (b, h, wp) pooled output; writes 32-channel bit word.
__global__ __launch_bounds__(256) void layer1_kernel(
    const float* __restrict__ x, const float* __restrict__ s1, const float* __restrict__ b1,
    const float* __restrict__ inv1, const float* __restrict__ sh1, u32* __restrict__ a1) {
    __shared__ float sS[288], sB[32], sI[32], sSh[32];
    int t = threadIdx.x;
    for (int i = t; i < 288; i += 256) sS[i] = s1[i];   // FIX: covers 256..287
    if (t < 32) { sB[t] = b1[t]; sI[t] = inv1[t]; sSh[t] = sh1[t]; }
    __syncthreads();
    int gid = blockIdx.x * 256 + t;          // total 8192*6*32
    int wp = gid & 31;
    int bh = gid >> 5;                       // b*6 + h
    const float* xp = x + (size_t)bh * 128;
    // conv outputs w0=2wp, w1=2wp+1; input positions 4wp-4 .. 4wp+6 (11 values, 0-pad OOB)
    float xv[11];
    int p0 = 4 * wp - 4;
#pragma unroll
    for (int j = 0; j < 11; ++j) {
        int p = p0 + j;
        xv[j] = (p >= 0 && p < 128) ? xp[p] : 0.f;
    }
    u32 word = 0;
#pragma unroll
    for (int co = 0; co < 32; ++co) {
        float sum0 = 0.f, sum1 = 0.f;
#pragma unroll
        for (int k = 0; k < 9; ++k) {
            float wv = sS[co * 9 + k];
            sum0 = fmaf(wv, xv[k], sum0);
            sum1 = fmaf(wv, xv[k + 2], sum1);
        }
        float y0 = __fadd_rn(__fmul_rn(__fadd_rn(sum0, sB[co]), sI[co]), sSh[co]);
        float y1 = __fadd_rn(__fmul_rn(__fadd_rn(sum1, sB[co]), sI[co]), sSh[co]);
        word |= (u32)((y0 >= 0.f) || (y1 >= 0.f)) << co;
    }
    a1[gid] = word;
}

// ---------------- layer 2: xnor-popcount conv (1x3, pad 1), 32ci -> 64co ----------------
__global__ __launch_bounds__(256) void layer2_kernel(
    const u32* __restrict__ a1, const u32* __restrict__ wt2, const float* __restrict__ b2,
    const float* __restrict__ inv2, const float* __restrict__ sh2, u64* __restrict__ a2) {
    __shared__ u32 sW[192];
    __shared__ float sB[64], sI[64], sSh[64];
    int t = threadIdx.x;
    if (t < 192) sW[t] = wt2[t];
    if (t < 64) { sB[t] = b2[t]; sI[t] = inv2[t]; sSh[t] = sh2[t]; }
    __syncthreads();
    int gid = blockIdx.x * 256 + t;          // total 8192*6*32
    int w = gid & 31;
    int bh = gid >> 5;
    const u32* ap = a1 + (size_t)bh * 32;
    u32 am = ap[w];
    bool vl = (w > 0), vr = (w < 31);
    u32 al = vl ? ap[w - 1] : 0u;
    u32 ar = vr ? ap[w + 1] : 0u;
    int base = 32 + (vl ? 32 : 0) + (vr ? 32 : 0);
    u64 word = 0;
#pragma unroll
    for (int co = 0; co < 64; ++co) {
        int p = __popc(am ^ sW[co * 3 + 1]);
        if (vl) p += __popc(al ^ sW[co * 3 + 0]);
        if (vr) p += __popc(ar ^ sW[co * 3 + 2]);
        float y = __fadd_rn(__fmul_rn(__fadd_rn((float)(base - 2 * p), sB[co]), sI[co]), sSh[co]);
        word |= (u64)(y >= 0.f) << co;
    }
    a2[gid] = word;
}

// ---------------- layer 3: xnor conv (1x3, pad 1) 64ci->128co + pool-OR ----------------
// One thread per (b, h, wp) pooled output; writes two 64-bit words (128 channels).
__global__ __launch_bounds__(256) void layer3_kernel(
    const u64* __restrict__ a2, const u64* __restrict__ wt3, const float* __restrict__ b3,
    const float* __restrict__ inv3, const float* __restrict__ sh3, u64* __restrict__ a3) {
    __shared__ u64 sW[384];
    __shared__ float sB[128], sI[128], sSh[128];
    int t = threadIdx.x;
    for (int i = t; i < 384; i += 256) sW[i] = wt3[i];
    if (t < 128) { sB[t] = b3[t]; sI[t] = inv3[t]; sSh[t] = sh3[t]; }
    __syncthreads();
    int gid = blockIdx.x * 256 + t;          // total 8192*6*16
    int wp = gid & 15;
    int bh = gid >> 4;
    const u64* ap = a2 + (size_t)bh * 32;
    int w0 = 2 * wp, w1 = w0 + 1;
    bool vl = (w0 > 0), vr = (w1 < 31);
    u64 aL = vl ? ap[w0 - 1] : 0ull;
    u64 a0 = ap[w0];
    u64 a1w = ap[w1];
    u64 aR = vr ? ap[w1 + 1] : 0ull;
    int base0 = 64 * (2 + (vl ? 1 : 0));
    int base1 = 64 * (2 + (vr ? 1 : 0));
    u64 lo = 0, hi = 0;
#pragma unroll 8
    for (int co = 0; co < 128; ++co) {
        u64 wc0 = sW[co * 3 + 0], wc1 = sW[co * 3 + 1], wc2 = sW[co * 3 + 2];
        int pa = __popcll(a0 ^ wc1) + __popcll(a1w ^ wc2);
        if (vl) pa += __popcll(aL ^ wc0);
        int pb = __popcll(a0 ^ wc0) + __popcll(a1w ^ wc1);
        if (vr) pb += __popcll(aR ^ wc2);
        float y0 = __fadd_rn(__fmul_rn(__fadd_rn((float)(base0 - 2 * pa), sB[co]), sI[co]), sSh[co]);
        float y1 = __fadd_rn(__fmul_rn(__fadd_rn((float)(base1 - 2 * pb), sB[co]), sI[co]), sSh[co]);
        u64 bit = (u64)((y0 >= 0.f) || (y1 >= 0.f));
        if (co < 64) lo |= bit << co; else hi |= bit << (co - 64);
    }
    a3[(size_t)gid * 2 + 0] = lo;
    a3[(size_t)gid * 2 + 1] = hi;
}

// ---------------- layer 4 (6x1 conv, 128ci->128co) + FC (2048->10) ----------------
// Block of 256 threads handles 16 batches; thread t -> (bb = t>>4, w = t&15).
__global__ __launch_bounds__(256) void layer4_fc_kernel(
    const u64* __restrict__ a3, const u64* __restrict__ wt4, const float* __restrict__ b4,
    const float* __restrict__ inv4, const float* __restrict__ sh4,
    const u64* __restrict__ wtf, const float* __restrict__ bf, float* __restrict__ out) {
    __shared__ u64 sW4[1536];            // [co][h][j]
    __shared__ u64 sWf[320];             // [o][wi]
    __shared__ u64 sFeat[16][32];        // per batch 2048-bit feature
    __shared__ float sB[128], sI[128], sSh[128], sBf[10];
    int t = threadIdx.x;
    for (int i = t; i < 1536; i += 256) sW4[i] = wt4[i];
    for (int i = t; i < 320; i += 256) sWf[i] = wtf[i];
    if (t < 128) { sB[t] = b4[t]; sI[t] = inv4[t]; sSh[t] = sh4[t]; }
    if (t < 10) sBf[t] = bf[t];
    __syncthreads();

    int bb = t >> 4;          // batch within block (0..15)
    int w = t & 15;
    int lane = t & 63;
    int g = lane >> 4;        // 16-lane group within wave (batch within wave)
    int b = blockIdx.x * 16 + bb;
    // load this thread's a3 column: [h=0..5][j=0..1], layout b*192 + h*32 + w*2 + j
    u64 av[12];
#pragma unroll
    for (int h = 0; h < 6; ++h) {
        av[h * 2 + 0] = a3[(size_t)b * 192 + h * 32 + w * 2 + 0];
        av[h * 2 + 1] = a3[(size_t)b * 192 + h * 32 + w * 2 + 1];
    }
    u64 acc = 0;
    for (int co = 0; co < 128; ++co) {
        const u64* wr = &sW4[co * 12];
        int p = 0;
#pragma unroll
        for (int q = 0; q < 12; ++q) p += __popcll(av[q] ^ wr[q]);
        float y = __fadd_rn(__fmul_rn(__fadd_rn((float)(768 - 2 * p), sB[co]), sI[co]), sSh[co]);
        // feature f = co*16 + w ; word = co>>2 ; bit = (co&3)*16 + w
        u64 m = __ballot(y >= 0.f);                 // 4 batches x 16 w per wave
        u64 field = (m >> (g * 16)) & 0xFFFFull;    // this batch's 16 bits
        acc |= field << ((co & 3) << 4);
        if ((co & 3) == 3) {
            if (w == 0) sFeat[bb][co >> 2] = acc;
            acc = 0;
        }
    }
    __syncthreads();
    // FC: 16 batches x 10 outputs = 160 threads
    if (t < 160) {
        int fb = t / 10, o = t % 10;
        int p = 0;
#pragma unroll
        for (int wi = 0; wi < 32; ++wi) p += __popcll(sFeat[fb][wi] ^ sWf[o * 32 + wi]);
        out[(size_t)(blockIdx.x * 16 + fb) * 10 + o] = __fadd_rn((float)(2048 - 2 * p), sBf[o]);
    }
}

// ---------------- launch ----------------
extern "C" void kernel_launch(void* const* d_in, const int* in_sizes, int n_in,
                              void* d_out, int out_size, void* d_ws, size_t ws_size,
                              hipStream_t stream) {
    const float* x  = (const float*)d_in[0];
    const float* w1 = (const float*)d_in[1];  const float* b1 = (const float*)d_in[2];
    const float* w2 = (const float*)d_in[3];  const float* b2 = (const float*)d_in[4];
    const float* w3 = (const float*)d_in[5];  const float* b3 = (const float*)d_in[6];
    const float* w4 = (const float*)d_in[7];  const float* b4 = (const float*)d_in[8];
    const float* g1 = (const float*)d_in[9];  const float* be1 = (const float*)d_in[10];
    const float* m1 = (const float*)d_in[11]; const float* v1 = (const float*)d_in[12];
    const float* g2 = (const float*)d_in[13]; const float* be2 = (const float*)d_in[14];
    const float* m2 = (const float*)d_in[15]; const float* v2 = (const float*)d_in[16];
    const float* g3 = (const float*)d_in[17]; const float* be3 = (const float*)d_in[18];
    const float* m3 = (const float*)d_in[19]; const float* v3 = (const float*)d_in[20];
    const float* g4 = (const float*)d_in[21]; const float* be4 = (const float*)d_in[22];
    const float* m4 = (const float*)d_in[23]; const float* v4 = (const float*)d_in[24];
    const float* wf = (const float*)d_in[25]; const float* bf = (const float*)d_in[26];
    float* out = (float*)d_out;

    char* ws = (char*)d_ws;
    // big intermediates
    u32* a1 = (u32*)(ws + 0);                         // 8192*6*32 u32  = 6291456 B
    u64* a2 = (u64*)(ws + 6291456);                   // 8192*6*32 u64  = 12582912 B
    u64* a3 = (u64*)(ws + 18874368);                  // 8192*6*16*2 u64 = 12582912 B
    size_t S = 31457280;
    float* s1   = (float*)(ws + S + 0);       // 288 floats
    float* inv1 = (float*)(ws + S + 1280);    // 32
    float* sh1  = (float*)(ws + S + 1408);    // 32
    u32*   wt2  = (u32*)  (ws + S + 1536);    // 192
    float* inv2 = (float*)(ws + S + 2304);    // 64
    float* sh2  = (float*)(ws + S + 2560);    // 64
    u64*   wt3  = (u64*)  (ws + S + 2816);    // 384
    float* inv3 = (float*)(ws + S + 5888);    // 128
    float* sh3  = (float*)(ws + S + 6400);    // 128
    u64*   wt4  = (u64*)  (ws + S + 6912);    // 1536
    float* inv4 = (float*)(ws + S + 19200);   // 128
    float* sh4  = (float*)(ws + S + 19712);   // 128
    u64*   wtf  = (u64*)  (ws + S + 20224);   // 320

    prep_bn_all<<<1, 128, 0, stream>>>(g1, be1, m1, v1, g2, be2, m2, v2,
                                       g3, be3, m3, v3, g4, be4, m4, v4,
                                       inv1, sh1, inv2, sh2, inv3, sh3, inv4, sh4);
    prep_pack<<<6, 256, 0, stream>>>(w1, w2, w3, w4, wf, s1, wt2, wt3, wt4, wtf);

    layer1_kernel<<<(BATCH * 6 * 32) / 256, 256, 0, stream>>>(x, s1, b1, inv1, sh1, a1);
    layer2_kernel<<<(BATCH * 6 * 32) / 256, 256, 0, stream>>>(a1, wt2, b2, inv2, sh2, a2);
    layer3_kernel<<<(BATCH * 6 * 16) / 256, 256, 0, stream>>>(a2, wt3, b3, inv3, sh3, a3);
    layer4_fc_kernel<<<BATCH / 16, 256, 0, stream>>>(a3, wt4, b4, inv4, sh4, wtf, bf, out);
}

// Round 4
// 319.679 us; speedup vs baseline: 1.1998x; 1.1998x over previous
//
#include <hip/hip_runtime.h>
#include <cstdint>
#include <cstddef>

#define BN_EPS 1e-5f
#define BATCH 8192

typedef unsigned long long u64;
typedef uint32_t u32;

// float <-> total-order key (ascending with float order on finites)
__device__ __forceinline__ u32 f2k(float f) {
    u32 u = __float_as_uint(f);
    return (u >> 31) ? ~u : (u | 0x80000000u);
}
__device__ __forceinline__ float k2f(u32 k) {
    u32 u = (k & 0x80000000u) ? (k ^ 0x80000000u) : ~k;
    return __uint_as_float(u);
}
// exact fp32 BN chain — must match R3's layer kernels bit-for-bit
__device__ __forceinline__ float bn_eval(float conv, float B, float iv, float sh) {
    return __fadd_rn(__fmul_rn(__fadd_rn(conv, B), iv), sh);
}

// ---------------- one merged prep kernel ----------------
// Packs sign weights (complemented where BN slope iv<0 so that bit = (p <= T)
// uniformly) and computes exact integer sign-thresholds per (channel, edge
// class) by scanning every reachable integer conv value through the exact
// fp32 chain. Layer1 gets an exact fp32 threshold via total-order bisection.
__global__ __launch_bounds__(256) void prep_all(
    const float* w1, const float* b1, const float* w2, const float* b2,
    const float* w3, const float* b3, const float* w4, const float* b4,
    const float* wf,
    const float* g1, const float* be1, const float* m1, const float* v1,
    const float* g2, const float* be2, const float* m2, const float* v2,
    const float* g3, const float* be3, const float* m3, const float* v3,
    const float* g4, const float* be4, const float* m4, const float* v4,
    float* s1, float* T1, u32* wt2w, int* T2, u64* wt3v, int* T3,
    u64* wt4, int* T4, u64* wtf) {
    int t = blockIdx.x * 256 + threadIdx.x;

    if (t < 288) {
        // layer1 sign weights, slope-folded: s1' = d * sign(w1), d = sign(iv1)
        int co = t / 9;
        float iv = g1[co] * rsqrtf(v1[co] + BN_EPS);
        float d = (iv < 0.f) ? -1.f : 1.f;
        s1[t] = ((w1[t] >= 0.f) ? 1.f : -1.f) * d;
    } else if (t < 320) {
        // layer1 fp threshold: bit = (sum' >= T1[co]); pred monotone in sum'
        int co = t - 288;
        float iv = g1[co] * rsqrtf(v1[co] + BN_EPS);
        float sh = be1[co] - m1[co] * iv;
        float B = b1[co];
        bool flip = (iv < 0.f);
        auto pred = [&](float sp) {
            float sum = flip ? -sp : sp;   // exact negation
            return bn_eval(sum, B, iv, sh) >= 0.f;
        };
        u32 lo = f2k(-3.0e38f), hi = f2k(3.0e38f);
        float Tv;
        if (pred(k2f(lo))) Tv = k2f(lo);
        else if (!pred(k2f(hi))) Tv = __uint_as_float(0x7F800000u);  // +inf: never
        else {
            while (hi - lo > 1u) {
                u32 mid = lo + ((hi - lo) >> 1);
                if (pred(k2f(mid))) hi = mid; else lo = mid;
            }
            Tv = k2f(hi);
        }
        T1[co] = Tv;
    } else if (t < 512) {
        // layer2 packed (possibly complemented) weights: [co][kw] in u32x4 rows
        int idx = t - 320;
        int co = idx / 3, kw = idx % 3;
        float iv = g2[co] * rsqrtf(v2[co] + BN_EPS);
        bool flip = (iv < 0.f);
        u32 wb = 0;
        for (int ci = 0; ci < 32; ++ci)
            wb |= (u32)((w2[(co * 32 + ci) * 3 + kw] >= 0.f) != flip) << ci;
        wt2w[co * 4 + kw] = wb;
    } else if (t < 704) {
        // layer2 thresholds: cls 0=interior, 1=left edge (w=0), 2=right edge (w=31)
        int idx = t - 512;
        int co = idx & 63, cls = idx >> 6;
        float iv = g2[co] * rsqrtf(v2[co] + BN_EPS);
        float sh = be2[co] - m2[co] * iv;
        float B = b2[co];
        bool flip = (iv < 0.f);
        int spur = 0, nv = 3;
        if (cls == 1) { nv = 2; for (int ci = 0; ci < 32; ++ci) spur += (int)((w2[(co * 32 + ci) * 3 + 0] >= 0.f) != flip); }
        if (cls == 2) { nv = 2; for (int ci = 0; ci < 32; ++ci) spur += (int)((w2[(co * 32 + ci) * 3 + 2] >= 0.f) != flip); }
        int maxp = 32 * nv + spur;
        int T = -1;
        for (int p = 0; p <= maxp; ++p) {
            int conv = flip ? (2 * (p - spur) - 32 * nv) : (32 * nv - 2 * (p - spur));
            float y = bn_eval((float)conv, B, iv, sh);
            if ((y >= 0.f) && (T == p - 1)) T = p;   // largest true prefix
        }
        T2[cls * 64 + co] = T;
    } else if (t < 1088) {
        // layer3 packed weights: [co][kw] in u64x4 rows
        int idx = t - 704;
        int co = idx / 3, kw = idx % 3;
        float iv = g3[co] * rsqrtf(v3[co] + BN_EPS);
        bool flip = (iv < 0.f);
        u64 wb = 0;
        for (int ci = 0; ci < 64; ++ci)
            wb |= (u64)((w3[(co * 64 + ci) * 3 + kw] >= 0.f) != flip) << ci;
        wt3v[co * 4 + kw] = wb;
    } else if (t < 1472) {
        // layer3 thresholds: cls 0=interior, 1=left (pa at wp=0), 2=right (pb at wp=15)
        int idx = t - 1088;
        int co = idx & 127, cls = idx >> 7;
        float iv = g3[co] * rsqrtf(v3[co] + BN_EPS);
        float sh = be3[co] - m3[co] * iv;
        float B = b3[co];
        bool flip = (iv < 0.f);
        int spur = 0, nv = 3;
        if (cls == 1) { nv = 2; for (int ci = 0; ci < 64; ++ci) spur += (int)((w3[(co * 64 + ci) * 3 + 0] >= 0.f) != flip); }
        if (cls == 2) { nv = 2; for (int ci = 0; ci < 64; ++ci) spur += (int)((w3[(co * 64 + ci) * 3 + 2] >= 0.f) != flip); }
        int maxp = 64 * nv + spur;
        int T = -1;
        for (int p = 0; p <= maxp; ++p) {
            int conv = flip ? (2 * (p - spur) - 64 * nv) : (64 * nv - 2 * (p - spur));
            float y = bn_eval((float)conv, B, iv, sh);
            if ((y >= 0.f) && (T == p - 1)) T = p;
        }
        T3[cls * 128 + co] = T;
    } else if (t < 3008) {
        // layer4 packed weights: [(co*6+h)*2+j], bit cb = ci - j*64
        int idx = t - 1472;
        int j = idx & 1, ch = idx >> 1;
        int co = ch / 6, h = ch % 6;
        float iv = g4[co] * rsqrtf(v4[co] + BN_EPS);
        bool flip = (iv < 0.f);
        u64 wb = 0;
        for (int cb = 0; cb < 64; ++cb) {
            int ci = j * 64 + cb;
            wb |= (u64)((w4[(co * 128 + ci) * 6 + h] >= 0.f) != flip) << cb;
        }
        wt4[idx] = wb;
    } else if (t < 3136) {
        // layer4 thresholds (single class, base 768, no padding)
        int co = t - 3008;
        float iv = g4[co] * rsqrtf(v4[co] + BN_EPS);
        float sh = be4[co] - m4[co] * iv;
        float B = b4[co];
        bool flip = (iv < 0.f);
        int T = -1;
        for (int p = 0; p <= 768; ++p) {
            int conv = flip ? (2 * p - 768) : (768 - 2 * p);
            float y = bn_eval((float)conv, B, iv, sh);
            if ((y >= 0.f) && (T == p - 1)) T = p;
        }
        T4[co] = T;
    } else if (t < 3456) {
        // fc weights (no flip — fp output)
        int idx = t - 3136;
        int o = idx / 32, wi = idx % 32;
        u64 wb = 0;
        for (int fb = 0; fb < 64; ++fb)
            wb |= (u64)(wf[o * 2048 + wi * 64 + fb] >= 0.f) << fb;
        wtf[idx] = wb;
    }
}

// ---------------- layer 1: fp32 conv (1x9, s2, p4) + threshold sign + pool-OR ----------------
__global__ __launch_bounds__(256) void layer1_kernel(
    const float* __restrict__ x, const float* __restrict__ s1, const float* __restrict__ T1,
    u32* __restrict__ a1) {
    __shared__ float sS[288], sT[32];
    int t = threadIdx.x;
    for (int i = t; i < 288; i += 256) sS[i] = s1[i];
    if (t < 32) sT[t] = T1[t];
    __syncthreads();
    int gid = blockIdx.x * 256 + t;          // total 8192*6*32
    int wp = gid & 31;
    int bh = gid >> 5;
    const float* xp = x + (size_t)bh * 128;
    float xv[11];
    int p0 = 4 * wp - 4;
#pragma unroll
    for (int j = 0; j < 11; ++j) {
        int p = p0 + j;
        xv[j] = (p >= 0 && p < 128) ? xp[p] : 0.f;
    }
    u32 word = 0;
#pragma unroll
    for (int co = 0; co < 32; ++co) {
        float sum0 = 0.f, sum1 = 0.f;
#pragma unroll
        for (int k = 0; k < 9; ++k) {
            float wv = sS[co * 9 + k];
            sum0 = fmaf(wv, xv[k], sum0);
            sum1 = fmaf(wv, xv[k + 2], sum1);
        }
        float Tt = sT[co];
        word |= (u32)((sum0 >= Tt) || (sum1 >= Tt)) << co;
    }
    a1[gid] = word;
}

// ---------------- layer 2: xnor conv (1x3, p1) 32ci->64co, threshold sign ----------------
__global__ __launch_bounds__(256) void layer2_kernel(
    const u32* __restrict__ a1, const uint4* __restrict__ wt2v, const int* __restrict__ T2,
    u64* __restrict__ a2) {
    __shared__ uint4 sW[64];
    __shared__ int sT[192];
    int t = threadIdx.x;
    if (t < 64) sW[t] = wt2v[t];
    if (t < 192) sT[t] = T2[t];
    __syncthreads();
    int gid = blockIdx.x * 256 + t;          // total 8192*6*32
    int w = gid & 31;
    int bh = gid >> 5;
    const u32* ap = a1 + (size_t)bh * 32;
    u32 am = ap[w];
    u32 al = (w > 0) ? ap[w - 1] : 0u;
    u32 ar = (w < 31) ? ap[w + 1] : 0u;
    const int* Tp = &sT[(w == 0) ? 64 : ((w == 31) ? 128 : 0)];
    u64 word = 0;
#pragma unroll
    for (int co = 0; co < 64; ++co) {
        uint4 wv = sW[co];
        int p = __popc(al ^ wv.x) + __popc(am ^ wv.y) + __popc(ar ^ wv.z);
        word |= (u64)(p <= Tp[co]) << co;
    }
    a2[gid] = word;
}

// ---------------- layer 3: xnor conv (1x3, p1) 64ci->128co + pool-OR, threshold sign ----------------
__global__ __launch_bounds__(256) void layer3_kernel(
    const u64* __restrict__ a2, const u64* __restrict__ wt3v, const int* __restrict__ T3,
    u64* __restrict__ a3) {
    __shared__ ulonglong2 sW[256];           // [co*2 + half]: {wc0,wc1},{wc2,pad}
    __shared__ int sT3[384];
    __shared__ int2 sTab[3][128];            // per class: (Ta, Tb)
    int t = threadIdx.x;
    sW[t] = ((const ulonglong2*)wt3v)[t];
    for (int i = t; i < 384; i += 256) sT3[i] = T3[i];
    __syncthreads();
    for (int i = t; i < 384; i += 256) {
        int cls = i >> 7, co = i & 127;
        int Ta = (cls == 1) ? sT3[128 + co] : sT3[co];
        int Tb = (cls == 2) ? sT3[256 + co] : sT3[co];
        sTab[cls][co] = make_int2(Ta, Tb);
    }
    __syncthreads();
    int gid = blockIdx.x * 256 + t;          // total 8192*6*16
    int wp = gid & 15;
    int bh = gid >> 4;
    const u64* ap = a2 + (size_t)bh * 32;
    int w0 = 2 * wp, w1 = w0 + 1;
    u64 aL = (wp > 0) ? ap[w0 - 1] : 0ull;
    u64 a0 = ap[w0];
    u64 a1w = ap[w1];
    u64 aR = (wp < 15) ? ap[w1 + 1] : 0ull;
    int cls = (wp == 0) ? 1 : ((wp == 15) ? 2 : 0);
    const int2* Tp = sTab[cls];
    u64 lo = 0, hi = 0;
#pragma unroll 32
    for (int co = 0; co < 64; ++co) {
        ulonglong2 wA = sW[co * 2];
        u64 wc2 = sW[co * 2 + 1].x;
        int2 Tv = Tp[co];
        int pa = __popcll(aL ^ wA.x) + __popcll(a0 ^ wA.y) + __popcll(a1w ^ wc2);
        int pb = __popcll(a0 ^ wA.x) + __popcll(a1w ^ wA.y) + __popcll(aR ^ wc2);
        lo |= (u64)((pa <= Tv.x) || (pb <= Tv.y)) << co;
    }
#pragma unroll 32
    for (int co = 64; co < 128; ++co) {
        ulonglong2 wA = sW[co * 2];
        u64 wc2 = sW[co * 2 + 1].x;
        int2 Tv = Tp[co];
        int pa = __popcll(aL ^ wA.x) + __popcll(a0 ^ wA.y) + __popcll(a1w ^ wc2);
        int pb = __popcll(a0 ^ wA.x) + __popcll(a1w ^ wA.y) + __popcll(aR ^ wc2);
        hi |= (u64)((pa <= Tv.x) || (pb <= Tv.y)) << (co - 64);
    }
    a3[(size_t)gid * 2 + 0] = lo;
    a3[(size_t)gid * 2 + 1] = hi;
}

// ---------------- layer 4 (6x1 conv) + FC (2048->10) ----------------
__global__ __launch_bounds__(256) void layer4_fc_kernel(
    const u64* __restrict__ a3, const u64* __restrict__ wt4, const int* __restrict__ T4,
    const u64* __restrict__ wtf, const float* __restrict__ bf, float* __restrict__ out) {
    __shared__ u64 sW4[1536];
    __shared__ u64 sWf[320];
    __shared__ u64 sFeat[16][32];
    __shared__ int sT[128];
    __shared__ float sBf[10];
    int t = threadIdx.x;
    {
        ulonglong2* d = (ulonglong2*)sW4;
        const ulonglong2* s = (const ulonglong2*)wt4;
        for (int i = t; i < 768; i += 256) d[i] = s[i];
        ulonglong2* df = (ulonglong2*)sWf;
        const ulonglong2* sf = (const ulonglong2*)wtf;
        if (t < 160) df[t] = sf[t];
    }
    if (t < 128) sT[t] = T4[t];
    if (t < 10) sBf[t] = bf[t];
    __syncthreads();
    int bb = t >> 4, w = t & 15, lane = t & 63, g = lane >> 4;
    int b = blockIdx.x * 16 + bb;
    u64 av[12];
#pragma unroll
    for (int h = 0; h < 6; ++h) {
        av[h * 2 + 0] = a3[(size_t)b * 192 + h * 32 + w * 2 + 0];
        av[h * 2 + 1] = a3[(size_t)b * 192 + h * 32 + w * 2 + 1];
    }
    u64 acc = 0;
#pragma unroll 8
    for (int co = 0; co < 128; ++co) {
        const u64* wr = &sW4[co * 12];
        int p = 0;
#pragma unroll
        for (int q = 0; q < 12; ++q) p += __popcll(av[q] ^ wr[q]);
        u64 m = __ballot(p <= sT[co]);              // 4 batches x 16 w per wave
        u64 field = (m >> (g * 16)) & 0xFFFFull;
        acc |= field << ((co & 3) << 4);
        if ((co & 3) == 3) {
            if (w == 0) sFeat[bb][co >> 2] = acc;
            acc = 0;
        }
    }
    __syncthreads();
    if (t < 160) {
        int fb = t / 10, o = t % 10;
        int p = 0;
#pragma unroll
        for (int wi = 0; wi < 32; ++wi) p += __popcll(sFeat[fb][wi] ^ sWf[o * 32 + wi]);
        out[(size_t)(blockIdx.x * 16 + fb) * 10 + o] = __fadd_rn((float)(2048 - 2 * p), sBf[o]);
    }
}

// ---------------- launch ----------------
extern "C" void kernel_launch(void* const* d_in, const int* in_sizes, int n_in,
                              void* d_out, int out_size, void* d_ws, size_t ws_size,
                              hipStream_t stream) {
    const float* x  = (const float*)d_in[0];
    const float* w1 = (const float*)d_in[1];  const float* b1 = (const float*)d_in[2];
    const float* w2 = (const float*)d_in[3];  const float* b2 = (const float*)d_in[4];
    const float* w3 = (const float*)d_in[5];  const float* b3 = (const float*)d_in[6];
    const float* w4 = (const float*)d_in[7];  const float* b4 = (const float*)d_in[8];
    const float* g1 = (const float*)d_in[9];  const float* be1 = (const float*)d_in[10];
    const float* m1 = (const float*)d_in[11]; const float* v1 = (const float*)d_in[12];
    const float* g2 = (const float*)d_in[13]; const float* be2 = (const float*)d_in[14];
    const float* m2 = (const float*)d_in[15]; const float* v2 = (const float*)d_in[16];
    const float* g3 = (const float*)d_in[17]; const float* be3 = (const float*)d_in[18];
    const float* m3 = (const float*)d_in[19]; const float* v3 = (const float*)d_in[20];
    const float* g4 = (const float*)d_in[21]; const float* be4 = (const float*)d_in[22];
    const float* m4 = (const float*)d_in[23]; const float* v4 = (const float*)d_in[24];
    const float* wf = (const float*)d_in[25]; const float* bf = (const float*)d_in[26];
    float* out = (float*)d_out;

    char* ws = (char*)d_ws;
    u32* a1 = (u32*)(ws + 0);                 // 8192*6*32 u32  = 6291456 B
    u64* a2 = (u64*)(ws + 6291456);           // 8192*6*32 u64  = 12582912 B
    u64* a3 = (u64*)(ws + 18874368);          // 8192*6*16*2 u64 = 12582912 B
    const size_t S = 31457280;
    u64*  wt3v = (u64*) (ws + S + 0);         // 512 u64 (padded x4)     4096 B
    u64*  wt4  = (u64*) (ws + S + 4096);      // 1536 u64               12288 B
    u64*  wtf  = (u64*) (ws + S + 16384);     // 320 u64                 2560 B
    u32*  wt2w = (u32*) (ws + S + 18944);     // 256 u32 (padded x4)     1024 B
    float* s1  = (float*)(ws + S + 19968);    // 288 f                   1152 B
    float* T1  = (float*)(ws + S + 21120);    // 32 f
    int*  T2   = (int*)  (ws + S + 21248);    // 192 i32
    int*  T3   = (int*)  (ws + S + 22016);    // 384 i32
    int*  T4   = (int*)  (ws + S + 23552);    // 128 i32

    prep_all<<<14, 256, 0, stream>>>(w1, b1, w2, b2, w3, b3, w4, b4, wf,
                                     g1, be1, m1, v1, g2, be2, m2, v2,
                                     g3, be3, m3, v3, g4, be4, m4, v4,
                                     s1, T1, wt2w, T2, wt3v, T3, wt4, T4, wtf);

    layer1_kernel<<<(BATCH * 6 * 32) / 256, 256, 0, stream>>>(x, s1, T1, a1);
    layer2_kernel<<<(BATCH * 6 * 32) / 256, 256, 0, stream>>>(a1, (const uint4*)wt2w, T2, a2);
    layer3_kernel<<<(BATCH * 6 * 16) / 256, 256, 0, stream>>>(a2, wt3v, T3, a3);
    layer4_fc_kernel<<<BATCH / 16, 256, 0, stream>>>(a3, wt4, T4, wtf, bf, out);
}

// Round 5
// 277.164 us; speedup vs baseline: 1.3838x; 1.1534x over previous
//
#include <hip/hip_runtime.h>
#include <cstdint>
#include <cstddef>

#define BN_EPS 1e-5f
#define BATCH 8192

typedef unsigned long long u64;
typedef uint32_t u32;
typedef int v4i __attribute__((ext_vector_type(4)));
typedef int v16i __attribute__((ext_vector_type(16)));

// float <-> total-order key (ascending with float order on finites)
__device__ __forceinline__ u32 f2k(float f) {
    u32 u = __float_as_uint(f);
    return (u >> 31) ? ~u : (u | 0x80000000u);
}
__device__ __forceinline__ float k2f(u32 k) {
    u32 u = (k & 0x80000000u) ? (k ^ 0x80000000u) : ~k;
    return __uint_as_float(u);
}
// exact fp32 BN chain — bit-identical to the reference epilogue semantics
__device__ __forceinline__ float bn_eval(float conv, float B, float iv, float sh) {
    return __fadd_rn(__fmul_rn(__fadd_rn(conv, B), iv), sh);
}

// ---------------- one merged prep kernel ----------------
__global__ __launch_bounds__(256) void prep_all(
    const float* w1, const float* b1, const float* w2, const float* b2,
    const float* w3, const float* b3, const float* w4, const float* b4,
    const float* wf,
    const float* g1, const float* be1, const float* m1, const float* v1,
    const float* g2, const float* be2, const float* m2, const float* v2,
    const float* g3, const float* be3, const float* m3, const float* v3,
    const float* g4, const float* be4, const float* m4, const float* v4,
    float* s1, float* T1, u32* wt2w, int* T2,
    uint4* b3i8, int* C3, u64* wt4, int* T4, u64* wtf) {
    int t = blockIdx.x * 256 + threadIdx.x;

    if (t < 288) {
        // layer1 sign weights, slope-folded
        int co = t / 9;
        float iv = g1[co] * rsqrtf(v1[co] + BN_EPS);
        float d = (iv < 0.f) ? -1.f : 1.f;
        s1[t] = ((w1[t] >= 0.f) ? 1.f : -1.f) * d;
    } else if (t < 320) {
        // layer1 fp threshold via total-order bisection: bit = (sum' >= T1[co])
        int co = t - 288;
        float iv = g1[co] * rsqrtf(v1[co] + BN_EPS);
        float sh = be1[co] - m1[co] * iv;
        float B = b1[co];
        bool flip = (iv < 0.f);
        auto pred = [&](float sp) {
            float sum = flip ? -sp : sp;
            return bn_eval(sum, B, iv, sh) >= 0.f;
        };
        u32 lo = f2k(-3.0e38f), hi = f2k(3.0e38f);
        float Tv;
        if (pred(k2f(lo))) Tv = k2f(lo);
        else if (!pred(k2f(hi))) Tv = __uint_as_float(0x7F800000u);
        else {
            while (hi - lo > 1u) {
                u32 mid = lo + ((hi - lo) >> 1);
                if (pred(k2f(mid))) hi = mid; else lo = mid;
            }
            Tv = k2f(hi);
        }
        T1[co] = Tv;
    } else if (t < 512) {
        // layer2 packed (complemented if iv<0) weights: [co][kw] u32x4 rows
        int idx = t - 320;
        int co = idx / 3, kw = idx % 3;
        float iv = g2[co] * rsqrtf(v2[co] + BN_EPS);
        bool flip = (iv < 0.f);
        u32 wb = 0;
        for (int ci = 0; ci < 32; ++ci)
            wb |= (u32)((w2[(co * 32 + ci) * 3 + kw] >= 0.f) != flip) << ci;
        wt2w[co * 4 + kw] = wb;
    } else if (t < 704) {
        // layer2 thresholds: cls 0=interior, 1=left edge, 2=right edge
        int idx = t - 512;
        int co = idx & 63, cls = idx >> 6;
        float iv = g2[co] * rsqrtf(v2[co] + BN_EPS);
        float sh = be2[co] - m2[co] * iv;
        float B = b2[co];
        bool flip = (iv < 0.f);
        int spur = 0, nv = 3;
        if (cls == 1) { nv = 2; for (int ci = 0; ci < 32; ++ci) spur += (int)((w2[(co * 32 + ci) * 3 + 0] >= 0.f) != flip); }
        if (cls == 2) { nv = 2; for (int ci = 0; ci < 32; ++ci) spur += (int)((w2[(co * 32 + ci) * 3 + 2] >= 0.f) != flip); }
        int maxp = 32 * nv + spur;
        int T = -1;
        for (int p = 0; p <= maxp; ++p) {
            int conv = flip ? (2 * (p - spur) - 32 * nv) : (32 * nv - 2 * (p - spur));
            float y = bn_eval((float)conv, B, iv, sh);
            if ((y >= 0.f) && (T == p - 1)) T = p;
        }
        T2[cls * 64 + co] = T;
    } else if (t < 2240) {
        // layer3 B as i8 (+-1, sign-folded by sign(iv)): [q][n][16 bytes]
        // q in [0,12): k = q*16+j -> kw = q>>2, ci = (q&3)*16 + j ; n = co
        int idx = t - 704;
        int q = idx >> 7, n = idx & 127;
        float iv = g3[n] * rsqrtf(v3[n] + BN_EPS);
        bool flip = (iv < 0.f);
        int kw = q >> 2, ci0 = (q & 3) * 16;
        u32 wd[4] = {0, 0, 0, 0};
        for (int j = 0; j < 16; ++j) {
            int ci = ci0 + j;
            bool pos = (w3[(n * 64 + ci) * 3 + kw] >= 0.f) != flip;
            u32 byte = pos ? 0x01u : 0xFFu;
            wd[j >> 2] |= byte << (8 * (j & 3));
        }
        b3i8[idx] = make_uint4(wd[0], wd[1], wd[2], wd[3]);
    } else if (t < 2368) {
        // layer3 integer conv-threshold: bit <=> conv' >= C3[co]
        // (conv' uses sign-folded weights; padding contributes 0 so conv is even in [-192,192])
        int co = t - 2240;
        float iv = g3[co] * rsqrtf(v3[co] + BN_EPS);
        float sh = be3[co] - m3[co] * iv;
        float B = b3[co];
        int C = 1000;
        if (iv >= 0.f) {
            for (int v = -192; v <= 192; v += 2)
                if (bn_eval((float)v, B, iv, sh) >= 0.f) { C = v; break; }
        } else {
            for (int v = 192; v >= -192; v -= 2)
                if (bn_eval((float)v, B, iv, sh) >= 0.f) { C = -v; break; }
        }
        C3[co] = C;
    } else if (t < 3904) {
        // layer4 packed weights
        int idx = t - 2368;
        int j = idx & 1, ch = idx >> 1;
        int co = ch / 6, h = ch % 6;
        float iv = g4[co] * rsqrtf(v4[co] + BN_EPS);
        bool flip = (iv < 0.f);
        u64 wb = 0;
        for (int cb = 0; cb < 64; ++cb) {
            int ci = j * 64 + cb;
            wb |= (u64)((w4[(co * 128 + ci) * 6 + h] >= 0.f) != flip) << cb;
        }
        wt4[idx] = wb;
    } else if (t < 4032) {
        // layer4 thresholds
        int co = t - 3904;
        float iv = g4[co] * rsqrtf(v4[co] + BN_EPS);
        float sh = be4[co] - m4[co] * iv;
        float B = b4[co];
        bool flip = (iv < 0.f);
        int T = -1;
        for (int p = 0; p <= 768; ++p) {
            int conv = flip ? (2 * p - 768) : (768 - 2 * p);
            float y = bn_eval((float)conv, B, iv, sh);
            if ((y >= 0.f) && (T == p - 1)) T = p;
        }
        T4[co] = T;
    } else if (t < 4352) {
        // fc weights
        int idx = t - 4032;
        int o = idx / 32, wi = idx % 32;
        u64 wb = 0;
        for (int fb = 0; fb < 64; ++fb)
            wb |= (u64)(wf[o * 2048 + wi * 64 + fb] >= 0.f) << fb;
        wtf[idx] = wb;
    }
}

// ---------------- layer 1: fp32 conv + threshold sign + pool-OR ----------------
__global__ __launch_bounds__(256) void layer1_kernel(
    const float* __restrict__ x, const float* __restrict__ s1, const float* __restrict__ T1,
    u32* __restrict__ a1) {
    __shared__ float sS[288], sT[32];
    int t = threadIdx.x;
    for (int i = t; i < 288; i += 256) sS[i] = s1[i];
    if (t < 32) sT[t] = T1[t];
    __syncthreads();
    int gid = blockIdx.x * 256 + t;
    int wp = gid & 31;
    int bh = gid >> 5;
    const float* xp = x + (size_t)bh * 128;
    float xv[11];
    int p0 = 4 * wp - 4;
#pragma unroll
    for (int j = 0; j < 11; ++j) {
        int p = p0 + j;
        xv[j] = (p >= 0 && p < 128) ? xp[p] : 0.f;
    }
    u32 word = 0;
#pragma unroll
    for (int co = 0; co < 32; ++co) {
        float sum0 = 0.f, sum1 = 0.f;
#pragma unroll
        for (int k = 0; k < 9; ++k) {
            float wv = sS[co * 9 + k];
            sum0 = fmaf(wv, xv[k], sum0);
            sum1 = fmaf(wv, xv[k + 2], sum1);
        }
        float Tt = sT[co];
        word |= (u32)((sum0 >= Tt) || (sum1 >= Tt)) << co;
    }
    a1[gid] = word;
}

// ---------------- layer 2: xnor conv 32ci->64co, threshold sign ----------------
__global__ __launch_bounds__(256) void layer2_kernel(
    const u32* __restrict__ a1, const uint4* __restrict__ wt2v, const int* __restrict__ T2,
    u64* __restrict__ a2) {
    __shared__ uint4 sW[64];
    __shared__ int sT[192];
    int t = threadIdx.x;
    if (t < 64) sW[t] = wt2v[t];
    if (t < 192) sT[t] = T2[t];
    __syncthreads();
    int gid = blockIdx.x * 256 + t;
    int w = gid & 31;
    int bh = gid >> 5;
    const u32* ap = a1 + (size_t)bh * 32;
    u32 am = ap[w];
    u32 al = (w > 0) ? ap[w - 1] : 0u;
    u32 ar = (w < 31) ? ap[w + 1] : 0u;
    const int* Tp = &sT[(w == 0) ? 64 : ((w == 31) ? 128 : 0)];
    u64 word = 0;
#pragma unroll
    for (int co = 0; co < 64; ++co) {
        uint4 wv = sW[co];
        int p = __popc(al ^ wv.x) + __popc(am ^ wv.y) + __popc(ar ^ wv.z);
        word |= (u64)(p <= Tp[co]) << co;
    }
    a2[gid] = word;
}

// ---------------- layer 3: i8 MFMA conv (1x3, p1) 64ci->128co + pool-OR ----------------
// One wave per (b,h) row: M=32 positions, N=128 co, K=192 (3 taps x 64 ci).
// A: +-1 i8 from bit-packed a2 (0 at pad) via LDS LUT; B: pre-expanded i8 in LDS.
// v_mfma_i32_32x32x32_i8 fragment model: A m=lane&31, k=(lane>>5)*16 + byte j;
// B n=lane&31, same k; C col=lane&31, row=(reg&3)+8*(reg>>2)+4*(lane>>5).
#define L3_ROWS 8
__global__ __launch_bounds__(256) void layer3_mfma(
    const u64* __restrict__ a2, const uint4* __restrict__ b3i8, const int* __restrict__ C3,
    u32* __restrict__ a3u32) {
    __shared__ uint4 sB[12 * 128];    // [q*128 + n][16 i8]  (24576 B)
    __shared__ u64 sLUT[256];         // byte -> 8 bytes of +1/-1
    __shared__ int sC3[128];
    int t = threadIdx.x;
    for (int i = t; i < 1536; i += 256) sB[i] = b3i8[i];
    {
        u32 b = t & 255;
        u64 e = 0;
#pragma unroll
        for (int j = 0; j < 8; ++j)
            e |= (((b >> j) & 1) ? 0x01ull : 0xFFull) << (8 * j);
        if (t < 256) sLUT[t] = e;
    }
    if (t < 128) sC3[t] = C3[t];
    __syncthreads();

    int wv = t >> 6, lane = t & 63, m = lane & 31, half = lane >> 5;
    int rowBase = (blockIdx.x * 4 + wv) * L3_ROWS;
    const int prTab[8] = {0, 1, 4, 5, 8, 9, 12, 13};

    for (int r = 0; r < L3_ROWS; ++r) {
        int bh = rowBase + r;
        u64 aw = a2[(size_t)bh * 32 + m];
        u64 wm1 = __shfl(aw, m - 1);   // m=0 -> pad (masked below)
        u64 wp1 = __shfl(aw, m + 1);   // m=31 -> pad (masked below)

        v4i A[6];
#pragma unroll
        for (int kk = 0; kk < 6; ++kk) {
            const int kw = kk >> 1;
            u64 word = (kw == 0) ? wm1 : ((kw == 1) ? aw : wp1);
            bool valid = !((kw == 0 && m == 0) || (kw == 2 && m == 31));
            int ci0 = ((kk & 1) << 5) + (half << 4);
            u32 bits = (u32)(word >> ci0) & 0xFFFFu;
            u64 lo = sLUT[bits & 0xFF];
            u64 hi = sLUT[bits >> 8];
            if (!valid) { lo = 0; hi = 0; }
            union { u64 q[2]; v4i v; } u;
            u.q[0] = lo; u.q[1] = hi;
            A[kk] = u.v;
        }

        u32 outv = 0;
#pragma unroll
        for (int nt = 0; nt < 4; ++nt) {
            v16i acc;
#pragma unroll
            for (int i = 0; i < 16; ++i) acc[i] = 0;
#pragma unroll
            for (int kk = 0; kk < 6; ++kk) {
                int q = kk * 2 + half;
                union { uint4 u4; v4i v; } bu;
                bu.u4 = sB[q * 128 + nt * 32 + m];
                acc = __builtin_amdgcn_mfma_i32_32x32x32_i8(A[kk], bu.v, acc, 0, 0, 0);
            }
            int tc = sC3[nt * 32 + m];
#pragma unroll
            for (int rp = 0; rp < 8; ++rp) {
                bool c = (acc[2 * rp] >= tc) || (acc[2 * rp + 1] >= tc);
                u64 mk = __ballot(c);
                int LA = (nt << 4) | prTab[rp];
                int LB = LA + 2;
                outv = (lane == LA) ? (u32)mk : outv;
                outv = (lane == LB) ? (u32)(mk >> 32) : outv;
            }
        }
        // a3 word layout matches layer4: u32 index = bh*64 + pr*4 + nt
        a3u32[(size_t)bh * 64 + ((lane & 15) << 2) + (lane >> 4)] = outv;
    }
}

// ---------------- layer 4 (6x1 conv) + FC (2048->10) ----------------
__global__ __launch_bounds__(256) void layer4_fc_kernel(
    const u64* __restrict__ a3, const u64* __restrict__ wt4, const int* __restrict__ T4,
    const u64* __restrict__ wtf, const float* __restrict__ bf, float* __restrict__ out) {
    __shared__ u64 sW4[1536];
    __shared__ u64 sWf[320];
    __shared__ u64 sFeat[16][32];
    __shared__ int sT[128];
    __shared__ float sBf[10];
    int t = threadIdx.x;
    {
        ulonglong2* d = (ulonglong2*)sW4;
        const ulonglong2* s = (const ulonglong2*)wt4;
        for (int i = t; i < 768; i += 256) d[i] = s[i];
        ulonglong2* df = (ulonglong2*)sWf;
        const ulonglong2* sf = (const ulonglong2*)wtf;
        if (t < 160) df[t] = sf[t];
    }
    if (t < 128) sT[t] = T4[t];
    if (t < 10) sBf[t] = bf[t];
    __syncthreads();
    int bb = t >> 4, w = t & 15, lane = t & 63, g = lane >> 4;
    int b = blockIdx.x * 16 + bb;
    u64 av[12];
#pragma unroll
    for (int h = 0; h < 6; ++h) {
        av[h * 2 + 0] = a3[(size_t)b * 192 + h * 32 + w * 2 + 0];
        av[h * 2 + 1] = a3[(size_t)b * 192 + h * 32 + w * 2 + 1];
    }
    u64 acc = 0;
#pragma unroll 8
    for (int co = 0; co < 128; ++co) {
        const u64* wr = &sW4[co * 12];
        int p = 0;
#pragma unroll
        for (int q = 0; q < 12; ++q) p += __popcll(av[q] ^ wr[q]);
        u64 m = __ballot(p <= sT[co]);
        u64 field = (m >> (g * 16)) & 0xFFFFull;
        acc |= field << ((co & 3) << 4);
        if ((co & 3) == 3) {
            if (w == 0) sFeat[bb][co >> 2] = acc;
            acc = 0;
        }
    }
    __syncthreads();
    if (t < 160) {
        int fb = t / 10, o = t % 10;
        int p = 0;
#pragma unroll
        for (int wi = 0; wi < 32; ++wi) p += __popcll(sFeat[fb][wi] ^ sWf[o * 32 + wi]);
        out[(size_t)(blockIdx.x * 16 + fb) * 10 + o] = __fadd_rn((float)(2048 - 2 * p), sBf[o]);
    }
}

// ---------------- launch ----------------
extern "C" void kernel_launch(void* const* d_in, const int* in_sizes, int n_in,
                              void* d_out, int out_size, void* d_ws, size_t ws_size,
                              hipStream_t stream) {
    const float* x  = (const float*)d_in[0];
    const float* w1 = (const float*)d_in[1];  const float* b1 = (const float*)d_in[2];
    const float* w2 = (const float*)d_in[3];  const float* b2 = (const float*)d_in[4];
    const float* w3 = (const float*)d_in[5];  const float* b3 = (const float*)d_in[6];
    const float* w4 = (const float*)d_in[7];  const float* b4 = (const float*)d_in[8];
    const float* g1 = (const float*)d_in[9];  const float* be1 = (const float*)d_in[10];
    const float* m1 = (const float*)d_in[11]; const float* v1 = (const float*)d_in[12];
    const float* g2 = (const float*)d_in[13]; const float* be2 = (const float*)d_in[14];
    const float* m2 = (const float*)d_in[15]; const float* v2 = (const float*)d_in[16];
    const float* g3 = (const float*)d_in[17]; const float* be3 = (const float*)d_in[18];
    const float* m3 = (const float*)d_in[19]; const float* v3 = (const float*)d_in[20];
    const float* g4 = (const float*)d_in[21]; const float* be4 = (const float*)d_in[22];
    const float* m4 = (const float*)d_in[23]; const float* v4 = (const float*)d_in[24];
    const float* wf = (const float*)d_in[25]; const float* bf = (const float*)d_in[26];
    float* out = (float*)d_out;

    char* ws = (char*)d_ws;
    u32* a1 = (u32*)(ws + 0);                 // 6291456 B
    u64* a2 = (u64*)(ws + 6291456);           // 12582912 B
    u64* a3 = (u64*)(ws + 18874368);          // 12582912 B
    const size_t S = 31457280;
    uint4* b3i8 = (uint4*)(ws + S + 0);       // 1536 x 16 B = 24576
    u64*  wt4  = (u64*) (ws + S + 24576);     // 12288 B
    u64*  wtf  = (u64*) (ws + S + 36864);     // 2560 B
    u32*  wt2w = (u32*) (ws + S + 39424);     // 1024 B
    float* s1  = (float*)(ws + S + 40448);    // 1152 B
    float* T1  = (float*)(ws + S + 41600);    // 128 B
    int*  T2   = (int*)  (ws + S + 41728);    // 768 B
    int*  C3   = (int*)  (ws + S + 42496);    // 512 B
    int*  T4   = (int*)  (ws + S + 43008);    // 512 B

    prep_all<<<17, 256, 0, stream>>>(w1, b1, w2, b2, w3, b3, w4, b4, wf,
                                     g1, be1, m1, v1, g2, be2, m2, v2,
                                     g3, be3, m3, v3, g4, be4, m4, v4,
                                     s1, T1, wt2w, T2, b3i8, C3, wt4, T4, wtf);

    layer1_kernel<<<(BATCH * 6 * 32) / 256, 256, 0, stream>>>(x, s1, T1, a1);
    layer2_kernel<<<(BATCH * 6 * 32) / 256, 256, 0, stream>>>(a1, (const uint4*)wt2w, T2, a2);
    layer3_mfma<<<(BATCH * 6) / (4 * L3_ROWS), 256, 0, stream>>>(a2, b3i8, C3, (u32*)a3);
    layer4_fc_kernel<<<BATCH / 16, 256, 0, stream>>>(a3, wt4, T4, wtf, bf, out);
}